// Round 3
// baseline (107.521 us; speedup 1.0000x reference)
//
#include <hip/hip_runtime.h>
#include <hip/hip_bf16.h>

// Problem constants (fixed by setup_inputs):
//   n = 4096, dc = 4096, nb = 4, db = 2048, T buckets = 5000
#define N_SAMP 4096
#define DC     4096
#define NB     4
#define DB     2048
#define TBKT   5000

#define CVEC (N_SAMP * DC / 4)   // 4,194,304 vec4 in common region
#define BVEC (N_SAMP * DB / 4)   // 2,097,152 vec4 per block region
#define TILE 4096                // vec4 per tile
#define WSEB 1024                // wse blocks; each owns 3 region-pure tiles

__device__ inline float ssq(const float4& x, const float4& y) {
    float d0 = x.x - y.x, d1 = x.y - y.y, d2 = x.z - y.z, d3 = x.w - y.w;
    return d0 * d0 + d1 * d1 + d2 * d2 + d3 * d3;
}

__device__ inline float block_reduce_sum(float v, volatile float* sm) {
    #pragma unroll
    for (int off = 32; off > 0; off >>= 1) v += __shfl_down(v, off);
    int lane = threadIdx.x & 63;
    int wid  = threadIdx.x >> 6;
    if (lane == 0) sm[wid] = v;
    __syncthreads();
    float r = 0.f;
    if (wid == 0) {
        r = (lane < 4) ? sm[lane] : 0.f;
        r += __shfl_down(r, 2);
        r += __shfl_down(r, 1);
    }
    return r;  // valid on thread 0
}

// Fused kernel. Blocks [0,WSEB): weighted-squared-error streaming reduction
// with a drain-free 2-slot register pipeline (8 float4 loads per chunk, 12
// chunks per block, steady-state vmcnt ~8). Blocks [WSEB, WSEB+5): the 5 Cox
// losses (tiny, run concurrently on 5 CUs). ws[0..4] accumulate wse sums.
__global__ __launch_bounds__(256) void fused_kernel(
    const float* __restrict__ pred,
    const float* __restrict__ ct, const float* __restrict__ cr,
    const float* __restrict__ bt, const float* __restrict__ br,
    const float* __restrict__ bh,
    const float* __restrict__ sw, const int* __restrict__ st,
    const int* __restrict__ se,
    float* __restrict__ ws, float* __restrict__ out)
{
    __shared__ float hist[TBKT];
    __shared__ float scan[256];
    __shared__ float smr[8];
    const int tid = threadIdx.x;

    if (blockIdx.x < WSEB) {
        const int b    = blockIdx.x;
        const int blk  = b >> 9;              // which pair of block-regions
        const int voff = (b & 511) * TILE;    // vec4 offset inside block region
        // tile 0: common region; tiles 1,2: block regions blk and 2+blk
        const float4* pa[3] = { (const float4*)ct,
                                (const float4*)bt + (size_t)blk * BVEC,
                                (const float4*)bt + (size_t)(2 + blk) * BVEC };
        const float4* pb[3] = { (const float4*)cr,
                                (const float4*)br + (size_t)blk * BVEC,
                                (const float4*)br + (size_t)(2 + blk) * BVEC };
        const int v[3] = { b * TILE, voff, voff };

        // Lane-uniform per-chunk weights (rows within a tile are uniform):
        // region0 chunk c covers row b*4+c; block tiles chunk c covers rows
        // (voff>>9)+2c and +2c+1. All scalar loads -> SGPRs.
        float wA[3][4], wB[3][4];
        {
            const int r0 = (b * TILE) >> 10;
            #pragma unroll
            for (int c = 0; c < 4; ++c) { float wv = sw[r0 + c]; wA[0][c] = wv; wB[0][c] = wv; }
            const int r1 = voff >> 9;
            #pragma unroll
            for (int c = 0; c < 4; ++c) {
                float wa = sw[r1 + 2 * c], wb = sw[r1 + 2 * c + 1];
                wA[1][c] = wa; wB[1][c] = wb;
                wA[2][c] = wa; wB[2][c] = wb;
            }
        }

        float4 A0[2], A1[2], A2[2], A3[2], B0[2], B1[2], B2[2], B3[2];
        float acc0 = 0.f, acc1 = 0.f, acc2 = 0.f;

#define PREF(S, T, C) do {                                                  \
        const int base_ = v[T] + (C) * 1024 + tid;                          \
        B0[S] = pb[T][base_];       B1[S] = pb[T][base_ + 256];             \
        B2[S] = pb[T][base_ + 512]; B3[S] = pb[T][base_ + 768];             \
        A0[S] = pa[T][base_];       A1[S] = pa[T][base_ + 256];             \
        A2[S] = pa[T][base_ + 512]; A3[S] = pa[T][base_ + 768];             \
    } while (0)
#define CONS(S, T, C, ACC) do {                                             \
        ACC += wA[T][C] * (ssq(B0[S], A0[S]) + ssq(B1[S], A1[S]))           \
             + wB[T][C] * (ssq(B2[S], A2[S]) + ssq(B3[S], A3[S]));          \
    } while (0)

        PREF(0, 0, 0);
        PREF(1, 0, 1); CONS(0, 0, 0, acc0);
        PREF(0, 0, 2); CONS(1, 0, 1, acc0);
        PREF(1, 0, 3); CONS(0, 0, 2, acc0);
        PREF(0, 1, 0); CONS(1, 0, 3, acc0);
        PREF(1, 1, 1); CONS(0, 1, 0, acc1);
        PREF(0, 1, 2); CONS(1, 1, 1, acc1);
        PREF(1, 1, 3); CONS(0, 1, 2, acc1);
        PREF(0, 2, 0); CONS(1, 1, 3, acc1);
        PREF(1, 2, 1); CONS(0, 2, 0, acc2);
        PREF(0, 2, 2); CONS(1, 2, 1, acc2);
        PREF(1, 2, 3); CONS(0, 2, 2, acc2);
                       CONS(1, 2, 3, acc2);
#undef PREF
#undef CONS

        float t0 = block_reduce_sum(acc0, smr);
        __syncthreads();
        float t1 = block_reduce_sum(acc1, smr);
        __syncthreads();
        float t2 = block_reduce_sum(acc2, smr);
        if (tid == 0) {
            atomicAdd(&ws[0], t0);
            atomicAdd(&ws[1 + blk], t1);
            atomicAdd(&ws[3 + blk], t2);
        }
        return;
    }

    // ---- Cox branch: one block per loss ----
    const int CH = 20;                 // 256*20 = 5120 >= 5000 buckets
    const int c  = blockIdx.x - WSEB;  // 0 -> pred, 1..4 -> block_hazards
    const float* p = (c == 0) ? pred : (bh + (size_t)(c - 1) * N_SAMP);

    for (int i = tid; i < TBKT; i += 256) hist[i] = 0.f;
    __syncthreads();

    for (int j = tid; j < N_SAMP; j += 256) {
        int t = st[j];
        t = (t < 0) ? 0 : ((t >= TBKT) ? TBKT - 1 : t);
        atomicAdd(&hist[t], expf(p[j]));
    }
    __syncthreads();

    // chunk sums
    const int base = tid * CH;
    float cs = 0.f;
    for (int i = base; i < base + CH && i < TBKT; ++i) cs += hist[i];
    scan[tid] = cs;
    __syncthreads();
    // Hillis-Steele suffix scan across 256 chunks
    for (int off = 1; off < 256; off <<= 1) {
        float vv = (tid + off < 256) ? scan[tid + off] : 0.f;
        __syncthreads();
        scan[tid] += vv;
        __syncthreads();
    }
    // within-chunk suffix; hist[t] becomes S[t] = sum_{u>=t} hist_orig[u]
    float run = (tid < 255) ? scan[tid + 1] : 0.f;
    int hi = base + CH; if (hi > TBKT) hi = TBKT;
    for (int i = hi - 1; i >= base; --i) { run += hist[i]; hist[i] = run; }
    __syncthreads();

    float s = 0.f, ne = 0.f;
    for (int j = tid; j < N_SAMP; j += 256) {
        float e = (float)se[j];
        int t = st[j];
        t = (t < 0) ? 0 : ((t >= TBKT) ? TBKT - 1 : t);
        s  += sw[j] * e * (p[j] - logf(hist[t]));
        ne += e;
    }
    float S  = block_reduce_sum(s,  smr);
    float NE = block_reduce_sum(ne, smr + 4);
    if (tid == 0) {
        float loss = (NE > 0.f) ? (-S / fmaxf(NE, 1.f)) : 0.f;
        out[(c == 0) ? 0 : (5 + c)] = loss;
    }
}

__global__ void finalize_kernel(const float* __restrict__ ws,
                                float* __restrict__ out)
{
    int i = threadIdx.x;
    if (i == 0)      out[1]     = ws[0] * (1.f / (float)DC);
    else if (i < 5)  out[1 + i] = ws[i] * (1.f / (float)DB);
}

extern "C" void kernel_launch(void* const* d_in, const int* in_sizes, int n_in,
                              void* d_out, int out_size, void* d_ws, size_t ws_size,
                              hipStream_t stream) {
    const float* pred = (const float*)d_in[0];
    const float* ct   = (const float*)d_in[1];
    const float* cr   = (const float*)d_in[2];
    const float* bt   = (const float*)d_in[3];
    const float* br   = (const float*)d_in[4];
    const float* bh   = (const float*)d_in[5];
    const float* sw   = (const float*)d_in[6];
    const int*   st   = (const int*)d_in[7];
    const int*   se   = (const int*)d_in[8];
    float* out = (float*)d_out;
    float* ws  = (float*)d_ws;

    hipMemsetAsync(ws, 0, 5 * sizeof(float), stream);

    fused_kernel<<<WSEB + 5, 256, 0, stream>>>(pred, ct, cr, bt, br, bh,
                                               sw, st, se, ws, out);
    finalize_kernel<<<1, 64, 0, stream>>>(ws, out);
}

// Round 5
// 83.214 us; speedup vs baseline: 1.2921x; 1.2921x over previous
//
#include <hip/hip_runtime.h>
#include <hip/hip_bf16.h>

// Problem constants (fixed by setup_inputs):
//   n = 4096, dc = 4096, nb = 4, db = 2048, T buckets = 5000
#define N_SAMP 4096
#define DC     4096
#define NB     4
#define DB     2048
#define TBKT   5000

#define CVEC (N_SAMP * DC / 4)   // 4,194,304 vec4 in common region
#define BVEC (N_SAMP * DB / 4)   // 2,097,152 vec4 per block region
#define TILE 4096                // vec4 per tile (region-pure)
#define NWSE ((CVEC + NB * BVEC) / TILE)  // 3072 wse tiles
#define NCOX 5

typedef float vf4 __attribute__((ext_vector_type(4)));  // builtin-compatible

__device__ inline float ssq(const vf4& x, const vf4& y) {
    float d0 = x.x - y.x, d1 = x.y - y.y, d2 = x.z - y.z, d3 = x.w - y.w;
    return d0 * d0 + d1 * d1 + d2 * d2 + d3 * d3;
}

__device__ inline float block_reduce_sum(float v, volatile float* sm) {
    #pragma unroll
    for (int off = 32; off > 0; off >>= 1) v += __shfl_down(v, off);
    int lane = threadIdx.x & 63;
    int wid  = threadIdx.x >> 6;
    if (lane == 0) sm[wid] = v;
    __syncthreads();
    float r = 0.f;
    if (wid == 0) {
        r = (lane < 4) ? sm[lane] : 0.f;
        r += __shfl_down(r, 2);
        r += __shfl_down(r, 1);
    }
    return r;  // valid on thread 0
}

// Fused kernel. Blocks [0,NCOX): the 5 Cox losses — placed FIRST so they
// dispatch before the wse flood and overlap with it. Blocks [NCOX, NCOX+NWSE):
// weighted-squared-error streaming reduction, R2-lean body (low VGPR), with
// nontemporal loads on the big streams (bypass L3 allocation -> pure HBM rate).
__global__ __launch_bounds__(256) void fused_kernel(
    const float* __restrict__ pred,
    const float* __restrict__ ct, const float* __restrict__ cr,
    const float* __restrict__ bt, const float* __restrict__ br,
    const float* __restrict__ bh,
    const float* __restrict__ sw, const int* __restrict__ st,
    const int* __restrict__ se,
    float* __restrict__ ws, float* __restrict__ out)
{
    __shared__ float hist[TBKT];
    __shared__ float scan[256];
    __shared__ float smr[8];
    const int tid = threadIdx.x;

    if (blockIdx.x >= NCOX) {
        const int tile = blockIdx.x - NCOX;
        const vf4* a;
        const vf4* b;
        int region, rowShift, vloc;
        if (tile < CVEC / TILE) {
            region = 0; rowShift = 10;       // 1024 vec4 per row
            a = (const vf4*)ct; b = (const vf4*)cr;
            vloc = tile * TILE;
        } else {
            const int q   = tile - CVEC / TILE;
            const int blk = q >> 9;          // 512 tiles per block region
            region = 1 + blk; rowShift = 9;  // 512 vec4 per row
            a = (const vf4*)bt + (size_t)blk * BVEC;
            b = (const vf4*)br + (size_t)blk * BVEC;
            vloc = (q & 511) * TILE;
        }
        const int v0 = vloc + tid;

        float acc = 0.f;
        #pragma unroll
        for (int outer = 0; outer < 2; ++outer) {
            vf4 xa[8], ya[8];
            float wv[8];
            const int base = v0 + outer * 2048;
            #pragma unroll
            for (int i = 0; i < 8; ++i) {
                xa[i] = __builtin_nontemporal_load(&b[base + i * 256]);
                ya[i] = __builtin_nontemporal_load(&a[base + i * 256]);
                wv[i] = sw[(base + i * 256) >> rowShift];
            }
            #pragma unroll
            for (int i = 0; i < 8; ++i)
                acc += wv[i] * ssq(xa[i], ya[i]);
        }

        float total = block_reduce_sum(acc, smr);
        if (tid == 0) atomicAdd(&ws[region], total);
        return;
    }

    // ---- Cox branch: one block per loss (blocks 0..4) ----
    const int CH = 20;                 // 256*20 = 5120 >= 5000 buckets
    const int c  = blockIdx.x;         // 0 -> pred, 1..4 -> block_hazards
    const float* p = (c == 0) ? pred : (bh + (size_t)(c - 1) * N_SAMP);

    for (int i = tid; i < TBKT; i += 256) hist[i] = 0.f;
    __syncthreads();

    for (int j = tid; j < N_SAMP; j += 256) {
        int t = st[j];
        t = (t < 0) ? 0 : ((t >= TBKT) ? TBKT - 1 : t);
        atomicAdd(&hist[t], expf(p[j]));
    }
    __syncthreads();

    // chunk sums
    const int base = tid * CH;
    float cs = 0.f;
    for (int i = base; i < base + CH && i < TBKT; ++i) cs += hist[i];
    scan[tid] = cs;
    __syncthreads();
    // Hillis-Steele suffix scan across 256 chunks
    for (int off = 1; off < 256; off <<= 1) {
        float vv = (tid + off < 256) ? scan[tid + off] : 0.f;
        __syncthreads();
        scan[tid] += vv;
        __syncthreads();
    }
    // within-chunk suffix; hist[t] becomes S[t] = sum_{u>=t} hist_orig[u]
    float run = (tid < 255) ? scan[tid + 1] : 0.f;
    int hi = base + CH; if (hi > TBKT) hi = TBKT;
    for (int i = hi - 1; i >= base; --i) { run += hist[i]; hist[i] = run; }
    __syncthreads();

    float s = 0.f, ne = 0.f;
    for (int j = tid; j < N_SAMP; j += 256) {
        float e = (float)se[j];
        int t = st[j];
        t = (t < 0) ? 0 : ((t >= TBKT) ? TBKT - 1 : t);
        s  += sw[j] * e * (p[j] - logf(hist[t]));
        ne += e;
    }
    float S  = block_reduce_sum(s,  smr);
    float NE = block_reduce_sum(ne, smr + 4);
    if (tid == 0) {
        float loss = (NE > 0.f) ? (-S / fmaxf(NE, 1.f)) : 0.f;
        out[(c == 0) ? 0 : (5 + c)] = loss;
    }
}

__global__ void finalize_kernel(const float* __restrict__ ws,
                                float* __restrict__ out)
{
    int i = threadIdx.x;
    if (i == 0)      out[1]     = ws[0] * (1.f / (float)DC);
    else if (i < 5)  out[1 + i] = ws[i] * (1.f / (float)DB);
}

extern "C" void kernel_launch(void* const* d_in, const int* in_sizes, int n_in,
                              void* d_out, int out_size, void* d_ws, size_t ws_size,
                              hipStream_t stream) {
    const float* pred = (const float*)d_in[0];
    const float* ct   = (const float*)d_in[1];
    const float* cr   = (const float*)d_in[2];
    const float* bt   = (const float*)d_in[3];
    const float* br   = (const float*)d_in[4];
    const float* bh   = (const float*)d_in[5];
    const float* sw   = (const float*)d_in[6];
    const int*   st   = (const int*)d_in[7];
    const int*   se   = (const int*)d_in[8];
    float* out = (float*)d_out;
    float* ws  = (float*)d_ws;

    hipMemsetAsync(ws, 0, 5 * sizeof(float), stream);

    fused_kernel<<<NWSE + NCOX, 256, 0, stream>>>(pred, ct, cr, bt, br, bh,
                                                  sw, st, se, ws, out);
    finalize_kernel<<<1, 64, 0, stream>>>(ws, out);
}